// Round 1
// 209.571 us; speedup vs baseline: 1.0588x; 1.0588x over previous
//
#include <hip/hip_runtime.h>
#include <math.h>

#define BLOCK 256
#define EPS 1e-6f

// R1 design notes (theory-first):
// - Bottleneck model: divergent-request throughput in the per-CU address pipe.
//   Old kernel: 4 divergent dwordx4/thread (2 per 32B node record) = 256 unique
//   sector requests/wave for the gather alone (~4.7 cy/req measured @97.6us).
// - Fix: cooperative gather via global_load_lds(16B). The two 16B halves of a
//   record are fetched by ADJACENT LANES of the SAME instruction -> TA
//   coalesces them into ONE 64B sector request (records are 32B-aligned).
//   128 req/wave instead of 256.
// - Everything is wave-private (pose staging, gather landing zone, out staging
//   reusing the gather region) -> ZERO __syncthreads in the hot path; only
//   s_waitcnt vmcnt(0) / lgkmcnt(0).
// - LDS slot swizzle slot(o,j2,h) = 4*o + ((2*j2+h) ^ ((o>>1)&3)) makes the
//   4x ds_read_b128 readback bank-balanced (slot%8 covers all 8 classes) while
//   keeping the two halves of a record at adjacent slots (= adjacent lanes on
//   the write side, required for the sector pairing).
// - Math: |qE|=1 => cos(theta)=w^2-n^2, sin(theta)=2nw =>
//   (1+cos)/(2*theta*sin) = w/(2*n*theta). sincosf eliminated exactly.

struct F3 { float x, y, z; };
struct F4 { float x, y, z, w; };

__device__ __forceinline__ F3 cross3(F3 a, F3 b) {
    return F3{a.y * b.z - a.z * b.y,
              a.z * b.x - a.x * b.z,
              a.x * b.y - a.y * b.x};
}
__device__ __forceinline__ F3 add3(F3 a, F3 b) { return F3{a.x + b.x, a.y + b.y, a.z + b.z}; }
__device__ __forceinline__ F3 neg3(F3 a) { return F3{-a.x, -a.y, -a.z}; }

__device__ __forceinline__ F3 qrot(F4 q, F3 v) {
    F3 u{q.x, q.y, q.z};
    F3 t = cross3(u, v);
    t.x *= 2.0f; t.y *= 2.0f; t.z *= 2.0f;
    F3 c = cross3(u, t);
    return F3{v.x + q.w * t.x + c.x,
              v.y + q.w * t.y + c.y,
              v.z + q.w * t.z + c.z};
}
__device__ __forceinline__ F4 qmul(F4 q, F4 r) {
    return F4{
        q.w * r.x + q.x * r.w + q.y * r.z - q.z * r.y,
        q.w * r.y - q.x * r.z + q.y * r.w + q.z * r.x,
        q.w * r.z + q.x * r.y - q.y * r.x + q.z * r.w,
        q.w * r.w - q.x * r.x - q.y * r.y - q.z * r.z};
}

// Full edge-error + se3_log, sincos-free (|qE| = 1 identities).
__device__ __forceinline__ void se3_error_log(
    F3 tp, F4 qp, F3 t1, F4 q1, F3 t2, F4 q2, float o[6])
{
    F4 qpc{-qp.x, -qp.y, -qp.z, qp.w};
    F3 tpi = neg3(qrot(qpc, tp));

    F3 tA = add3(tpi, qrot(qpc, t2));
    F4 qA = qmul(qpc, q2);

    F4 q1c{-q1.x, -q1.y, -q1.z, q1.w};
    F3 t1i = neg3(qrot(q1c, t1));

    F3 tE = add3(tA, qrot(qA, t1i));
    F4 qE = qmul(qA, q1c);

    F3 v{qE.x, qE.y, qE.z};
    float w = qE.w;
    float nn = sqrtf(v.x * v.x + v.y * v.y + v.z * v.z);

    float scale, c;
    if (nn > EPS) {
        float ang = 2.0f * atan2f(nn, w);   // == theta == |phi|
        float rn = 1.0f / nn;
        float ra = 1.0f / ang;
        scale = ang * rn;
        // cos(theta)=w^2-nn^2, sin(theta)=2*nn*w (unit qE)
        // => (1+cos)/(2*theta*sin) = w/(2*nn*theta)
        c = ra * ra - 0.5f * w * rn * ra;
    } else {
        // theta ~ 2*nn <= 2e-6: c-term multiplies O(theta^2) -> 1/12 exact limit
        scale = 2.0f / ((fabsf(w) > EPS) ? w : 1.0f);
        c = 1.0f / 12.0f;
    }

    F3 phi{v.x * scale, v.y * scale, v.z * scale};
    F3 pxt = cross3(phi, tE);
    F3 ppxt = cross3(phi, pxt);
    o[0] = tE.x - 0.5f * pxt.x + c * ppxt.x;
    o[1] = tE.y - 0.5f * pxt.y + c * ppxt.y;
    o[2] = tE.z - 0.5f * pxt.z + c * ppxt.z;
    o[3] = phi.x; o[4] = phi.y; o[5] = phi.z;
}

__device__ __forceinline__ void gload_lds16(const void* g, void* lds) {
    __builtin_amdgcn_global_load_lds(
        (const __attribute__((address_space(1))) void*)g,
        (__attribute__((address_space(3))) void*)lds,
        16, 0, 0);
}

// ---- prologue: nodes [N,7] -> d_ws [N,8] (32B records, 16B-aligned) ----
__global__ void __launch_bounds__(BLOCK) repack_nodes_kernel(
    const float* __restrict__ nodes, float* __restrict__ nodes8, int total7)
{
    int idx = blockIdx.x * BLOCK + threadIdx.x;
    int stride = gridDim.x * BLOCK;
    for (; idx < total7; idx += stride) {
        int node = idx / 7;
        int comp = idx - node * 7;
        nodes8[node * 8 + comp] = nodes[idx];
    }
}

__global__ void __launch_bounds__(BLOCK) pose_graph_kernel(
    const int* __restrict__ edges,     // [n,2] int32
    const float* __restrict__ poses,   // [n,7]
    const float* __restrict__ nodes8,  // [N_NODES,8] repacked
    float* __restrict__ out,           // [n,6]
    int n)
{
    __shared__ float4 SP[448];      // pose staging: 7168 B (wave w owns [112w,112w+112))
    __shared__ float4 G[4][256];    // gather landing + out staging: 16384 B (wave-private)

    const int tid = threadIdx.x;
    const int l = tid & 63;
    const int w = tid >> 6;
    const long long base = (long long)blockIdx.x * BLOCK;
    const int limit = (int)min((long long)BLOCK, (long long)n - base);

    if (limit == BLOCK) {
        // ---- edge indices (coalesced int2) ----
        const long long e = base + tid;
        const int2 ed = ((const int2*)edges)[e];

        // ---- pose staging: wave-private global_load_lds (no barrier needed) ----
        // wave w needs pose bytes [1792w, 1792(w+1)) of this block = 16B slots 112w..112w+111
        {
            const char* psrc = (const char*)poses + base * 28;
            gload_lds16(psrc + (size_t)(112 * w + l) * 16, &SP[112 * w]);
            if (l < 48)
                gload_lds16(psrc + (size_t)(112 * w + 64 + l) * 16, &SP[112 * w + 64]);
        }

        // ---- cooperative paired node gather, swizzled, wave-private ----
        // slot s = k*64 + l; owner lane o = s>>2; m = (s&3) ^ ((o>>1)&3);
        // j2 = m>>1 (node1/node2), h = m&1 (record half). Halves of one record
        // sit at adjacent slots (same instruction, adjacent lanes) -> 1 sector req.
#pragma unroll
        for (int k = 0; k < 4; ++k) {
            const int o = k * 16 + (l >> 2);
            const int m = (l & 3) ^ ((o >> 1) & 3);
            const int nx = __shfl(ed.x, o, 64);
            const int ny = __shfl(ed.y, o, 64);
            const int idx = (m & 2) ? ny : nx;
            gload_lds16((const char*)nodes8 + ((size_t)idx * 32 + (size_t)(m & 1) * 16),
                        &G[w][k * 64]);
        }

        // all global_load_lds for THIS wave's regions complete
        asm volatile("s_waitcnt vmcnt(0)" ::: "memory");

        // ---- read own pose (7 scalar LDS reads; stride 7 over banks = 2-way, free) ----
        const float* sp = (const float*)SP;
        const int p7 = tid * 7;
        F3 tp{sp[p7 + 0], sp[p7 + 1], sp[p7 + 2]};
        F4 qp{sp[p7 + 3], sp[p7 + 4], sp[p7 + 5], sp[p7 + 6]};

        // ---- read gathered nodes (swizzled slots; bank-balanced b128) ----
        const int xo = (l >> 1) & 3;
        const int b4 = l * 4;
        float4 a1 = G[w][b4 + (0 ^ xo)];   // node1 half0: t.xyz, q.x
        float4 b1 = G[w][b4 + (1 ^ xo)];   // node1 half1: q.yzw, pad
        float4 a2 = G[w][b4 + (2 ^ xo)];   // node2 half0
        float4 b2 = G[w][b4 + (3 ^ xo)];   // node2 half1

        F3 t1{a1.x, a1.y, a1.z};
        F4 q1{a1.w, b1.x, b1.y, b1.z};
        F3 t2{a2.x, a2.y, a2.z};
        F4 q2{a2.w, b2.x, b2.y, b2.z};

        float o6[6];
        se3_error_log(tp, qp, t1, q1, t2, q2, o6);

        // ---- out staging: reuse wave-private G[w] (gather data fully consumed;
        //      LDS ops from one wave are processed in order) ----
        float* Gf = (float*)&G[w][0];
        Gf[l * 6 + 0] = o6[0];
        Gf[l * 6 + 1] = o6[1];
        Gf[l * 6 + 2] = o6[2];
        Gf[l * 6 + 3] = o6[3];
        Gf[l * 6 + 4] = o6[4];
        Gf[l * 6 + 5] = o6[5];
        asm volatile("s_waitcnt lgkmcnt(0)" ::: "memory");  // own wave's ds_writes drained

        // coalesced wave-local store: wave w covers float4 slots [96w, 96w+96)
        float4* odst = (float4*)(out + base * 6);
        odst[w * 96 + l] = G[w][l];
        if (l < 32)
            odst[w * 96 + 64 + l] = G[w][64 + l];
    } else {
        // ---- tail block (absent at n=3.2M): simple per-thread scalar path ----
        if (tid < limit) {
            const long long e = base + tid;
            const int2 ed = ((const int2*)edges)[e];
            const float* pp = poses + e * 7;
            F3 tp{pp[0], pp[1], pp[2]};
            F4 qp{pp[3], pp[4], pp[5], pp[6]};
            const float4* n1p = (const float4*)(nodes8 + (size_t)ed.x * 8);
            const float4* n2p = (const float4*)(nodes8 + (size_t)ed.y * 8);
            float4 a1 = n1p[0], b1 = n1p[1];
            float4 a2 = n2p[0], b2 = n2p[1];
            F3 t1{a1.x, a1.y, a1.z};
            F4 q1{a1.w, b1.x, b1.y, b1.z};
            F3 t2{a2.x, a2.y, a2.z};
            F4 q2{a2.w, b2.x, b2.y, b2.z};
            float o6[6];
            se3_error_log(tp, qp, t1, q1, t2, q2, o6);
            float* op = out + e * 6;
            op[0] = o6[0]; op[1] = o6[1]; op[2] = o6[2];
            op[3] = o6[3]; op[4] = o6[4]; op[5] = o6[5];
        }
    }
}

// fallback (ws too small): direct scalar gathers from [N,7] nodes
__global__ void __launch_bounds__(BLOCK) pose_graph_kernel_fallback(
    const int* __restrict__ edges, const float* __restrict__ poses,
    const float* __restrict__ nodes, float* __restrict__ out, int n)
{
    const int tid = threadIdx.x;
    const long long base = (long long)blockIdx.x * BLOCK;
    const int limit = (int)min((long long)BLOCK, (long long)n - base);
    if (tid < limit) {
        const long long e = base + tid;
        const int2 ed = ((const int2*)edges)[e];
        const float* pp = poses + e * 7;
        F3 tp{pp[0], pp[1], pp[2]};
        F4 qp{pp[3], pp[4], pp[5], pp[6]};
        const float* n1p = nodes + (size_t)ed.x * 7;
        const float* n2p = nodes + (size_t)ed.y * 7;
        F3 t1{n1p[0], n1p[1], n1p[2]};
        F4 q1{n1p[3], n1p[4], n1p[5], n1p[6]};
        F3 t2{n2p[0], n2p[1], n2p[2]};
        F4 q2{n2p[3], n2p[4], n2p[5], n2p[6]};
        float o6[6];
        se3_error_log(tp, qp, t1, q1, t2, q2, o6);
        float* op = out + e * 6;
        op[0] = o6[0]; op[1] = o6[1]; op[2] = o6[2];
        op[3] = o6[3]; op[4] = o6[4]; op[5] = o6[5];
    }
}

extern "C" void kernel_launch(void* const* d_in, const int* in_sizes, int n_in,
                              void* d_out, int out_size, void* d_ws, size_t ws_size,
                              hipStream_t stream) {
    const int* edges = (const int*)d_in[0];
    const float* poses = (const float*)d_in[1];
    const float* nodes = (const float*)d_in[2];
    float* out = (float*)d_out;

    const int n_edges = in_sizes[0] / 2;
    const int n_nodes = in_sizes[2] / 7;
    const int grid = (n_edges + BLOCK - 1) / BLOCK;

    const size_t ws_needed = (size_t)n_nodes * 8 * sizeof(float);
    if (ws_size >= ws_needed) {
        float* nodes8 = (float*)d_ws;
        const int total7 = n_nodes * 7;
        const int rgrid = (total7 + BLOCK - 1) / BLOCK;
        repack_nodes_kernel<<<rgrid, BLOCK, 0, stream>>>(nodes, nodes8, total7);
        pose_graph_kernel<<<grid, BLOCK, 0, stream>>>(edges, poses, nodes8, out, n_edges);
    } else {
        pose_graph_kernel_fallback<<<grid, BLOCK, 0, stream>>>(edges, poses, nodes, out, n_edges);
    }
}